// Round 10
// baseline (495.156 us; speedup 1.0000x reference)
//
#include <hip/hip_runtime.h>
#include <hip/hip_bf16.h>

#define HDIM 128
#define H3   384
#define RDIM 20
#define NPB  16    // nodes per block (node MLP)
#define EPB  128   // edges per block (edge stream kernel)
#define TPB  384   // 3 roles x 128 channels

typedef unsigned short u16;
typedef unsigned int   u32;

__device__ __forceinline__ u16 f2bf(float f) {
    __hip_bfloat16 h = __float2bfloat16(f);   // RNE
    return *(u16*)&h;
}
__device__ __forceinline__ float bflo(u32 u) {
    union { u32 i; float f; } x; x.i = u << 16; return x.f;
}
__device__ __forceinline__ float bfhi(u32 u) {
    union { u32 i; float f; } x; x.i = u & 0xffff0000u; return x.f;
}
__device__ __forceinline__ u32 pk(float lo, float hi) {
    return (u32)f2bf(lo) | ((u32)f2bf(hi) << 16);
}

// -------- Kernel 1: per-node MLP -> packed bf16 P3[node][3][128]; fuses v conv --------
__global__ __launch_bounds__(128) void node_mlp_kernel(
    const float* __restrict__ s, const float* __restrict__ W1,
    const float* __restrict__ b1, const float* __restrict__ W2,
    const float* __restrict__ b2, const float* __restrict__ v,
    u32* __restrict__ P3, int N)
{
    __shared__ float sS[NPB][HDIM];
    __shared__ float sH[NPB][HDIM];
    const int t  = threadIdx.x;
    const int n0 = blockIdx.x * NPB;

    #pragma unroll
    for (int n = 0; n < NPB; ++n) {
        int node = n0 + n;
        sS[n][t] = (node < N) ? s[(size_t)node * HDIM + t] : 0.f;
    }
    __syncthreads();

    float acc[NPB];
    #pragma unroll
    for (int n = 0; n < NPB; ++n) acc[n] = 0.f;
    for (int k = 0; k < HDIM; ++k) {
        float w = W1[k * HDIM + t];
        #pragma unroll
        for (int n = 0; n < NPB; ++n) acc[n] += sS[n][k] * w;
    }
    float bb = b1[t];
    #pragma unroll
    for (int n = 0; n < NPB; ++n) {
        float z = acc[n] + bb;
        sH[n][t] = z / (1.f + __expf(-z));   // silu
    }
    __syncthreads();

    float a0[NPB], a1[NPB], a2[NPB];
    #pragma unroll
    for (int n = 0; n < NPB; ++n) { a0[n] = 0.f; a1[n] = 0.f; a2[n] = 0.f; }
    for (int k2 = 0; k2 < HDIM / 2; ++k2) {
        float2 hv[NPB];
        #pragma unroll
        for (int n = 0; n < NPB; ++n) hv[n] = ((const float2*)sH[n])[k2];
        #pragma unroll
        for (int kk = 0; kk < 2; ++kk) {
            int k = 2 * k2 + kk;
            float w0 = W2[k * H3 + t];
            float w1 = W2[k * H3 + t + 128];
            float w2 = W2[k * H3 + t + 256];
            #pragma unroll
            for (int n = 0; n < NPB; ++n) {
                float h = kk ? hv[n].y : hv[n].x;
                a0[n] += h * w0;
                a1[n] += h * w1;
                a2[n] += h * w2;
            }
        }
    }
    float c0 = b2[t], c1 = b2[t + 128], c2 = b2[t + 256];
    #pragma unroll
    for (int n = 0; n < NPB; ++n) {
        int node = n0 + n;
        if (node < N) {
            size_t vb = (size_t)node * H3;
            float vx = v[vb + t], vy = v[vb + 128 + t], vz = v[vb + 256 + t];
            size_t pb = (size_t)node * H3 + t;
            P3[pb]       = pk(a0[n] + c0, a1[n] + c1);   // (pss, psv)
            P3[pb + 128] = pk(a2[n] + c2, vx);           // (pvv, vx)
            P3[pb + 256] = pk(vy, vz);                   // (vy, vz)
        }
    }
}

// -------- CSR build (sort edges by destination) --------
__global__ void hist_kernel(const int* __restrict__ eidx, int* __restrict__ counts, int E)
{
    int e = blockIdx.x * 256 + threadIdx.x;
    if (e < E) atomicAdd(&counts[eidx[e]], 1);
}

__global__ __launch_bounds__(1024) void scan_kernel(
    const int* __restrict__ counts, int* __restrict__ rstart,
    int* __restrict__ cursor, int N)
{
    __shared__ int part[1024];
    const int t = threadIdx.x;
    const int C = 20;
    int loc[C];
    int s = 0;
    #pragma unroll
    for (int q = 0; q < C; ++q) {
        int idx = t * C + q;
        int c = (idx < N) ? counts[idx] : 0;
        loc[q] = s; s += c;
    }
    part[t] = s;
    __syncthreads();
    for (int off = 1; off < 1024; off <<= 1) {
        int vv = (t >= off) ? part[t - off] : 0;
        __syncthreads();
        part[t] += vv;
        __syncthreads();
    }
    int boff = (t > 0) ? part[t - 1] : 0;
    #pragma unroll
    for (int q = 0; q < C; ++q) {
        int idx = t * C + q;
        if (idx < N) {
            int st = boff + loc[q];
            rstart[idx] = st;
            cursor[idx] = st;
        }
    }
    if (t == 1023) rstart[N] = part[1023];
}

__global__ void scatter_kernel(const int* __restrict__ eidx, int* __restrict__ cursor,
                               int* __restrict__ eord, int E)
{
    int e = blockIdx.x * 256 + threadIdx.x;
    if (e < E) {
        int i = eidx[e];
        int pos = atomicAdd(&cursor[i], 1);
        eord[pos] = e;
    }
}

#define LOAD_ROW(dst, q) {                                           \
    const float4* rp = (const float4*)(rbf + (size_t)sE[q] * RDIM);  \
    dst[0]=rp[0]; dst[1]=rp[1]; dst[2]=rp[2]; dst[3]=rp[3]; dst[4]=rp[4]; }

#define DOT20(res, rr) {                                                         \
    res = brv;                                                                   \
    _Pragma("unroll")                                                            \
    for (int k4 = 0; k4 < 5; ++k4)                                               \
        res += rr[k4].x*wr[4*k4] + rr[k4].y*wr[4*k4+1] +                         \
               rr[k4].z*wr[4*k4+2] + rr[k4].w*wr[4*k4+3]; }

// -------- Kernel 2: edge streaming, 3 decoupled roles (1 output column/thread) --------
// Role 0: ds += xss. Role 1: dv += xsv*e. Role 2: dv += (inner*xvv)*e.
// The dv split is valid because both parts flush via atomicAdd.
__global__ __launch_bounds__(TPB) void edge_stream_kernel(
    const int* __restrict__ eord, const int* __restrict__ eidx,
    const float* __restrict__ rbf, const float* __restrict__ cutoff,
    const float* __restrict__ evec, const float* __restrict__ Wr,
    const float* __restrict__ br, const u32* __restrict__ P3,
    float* __restrict__ ds, float* __restrict__ dv, int E)
{
    const int t    = threadIdx.x;
    const int ch   = t & (HDIM - 1);
    const int role = t >> 7;            // 0,1,2
    const int base = blockIdx.x * EPB;
    const int cnt  = min(EPB, E - base);

    // 20 Wr values for this thread's single output column — fits in VGPRs
    float wr[RDIM];
    #pragma unroll
    for (int k = 0; k < RDIM; ++k) wr[k] = Wr[k * H3 + role * HDIM + ch];
    const float brv = br[role * HDIM + ch];

    __shared__ int   sE[EPB], sI[EPB], sJ[EPB];
    __shared__ float sCut[EPB], sVx[EPB], sVy[EPB], sVz[EPB];

    if (t < cnt) {
        int e   = eord[base + t];
        sE[t]   = e;
        sI[t]   = eidx[e];
        sJ[t]   = eidx[E + e] * H3;
        sCut[t] = cutoff[e];
        sVx[t]  = evec[3 * e];
        sVy[t]  = evec[3 * e + 1];
        sVz[t]  = evec[3 * e + 2];
    }
    __syncthreads();

    int cur = sI[0];

    if (role == 0) {
        float4 rc[5], rn[5];
        LOAD_ROW(rc, 0);
        #pragma unroll
        for (int j = 0; j < 5; ++j) rn[j] = rc[j];
        u32 ca = P3[sJ[0] + ch];
        float accs = 0.f;
        for (int q = 0; q < cnt; ++q) {
            int qn = q + 1;
            u32 na = 0;
            if (qn < cnt) { LOAD_ROW(rn, qn); na = P3[sJ[qn] + ch]; }
            if (sI[q] != cur) {                      // uniform branch
                atomicAdd(&ds[(size_t)cur * HDIM + ch], accs);
                accs = 0.f; cur = sI[q];
            }
            float w; DOT20(w, rc);
            accs += w * sCut[q] * bflo(ca);
            #pragma unroll
            for (int j = 0; j < 5; ++j) rc[j] = rn[j];
            ca = na;
        }
        atomicAdd(&ds[(size_t)cur * HDIM + ch], accs);
    } else if (role == 1) {
        float4 rc[5], rn[5];
        LOAD_ROW(rc, 0);
        #pragma unroll
        for (int j = 0; j < 5; ++j) rn[j] = rc[j];
        u32 ca = P3[sJ[0] + ch];                     // psv in hi half
        float ax = 0.f, ay = 0.f, az = 0.f;
        for (int q = 0; q < cnt; ++q) {
            int qn = q + 1;
            u32 na = 0;
            if (qn < cnt) { LOAD_ROW(rn, qn); na = P3[sJ[qn] + ch]; }
            if (sI[q] != cur) {
                size_t dvi = (size_t)cur * H3;
                atomicAdd(&dv[dvi + ch],       ax);
                atomicAdd(&dv[dvi + 128 + ch], ay);
                atomicAdd(&dv[dvi + 256 + ch], az);
                ax = ay = az = 0.f; cur = sI[q];
            }
            float w; DOT20(w, rc);
            float xsv = w * sCut[q] * bfhi(ca);
            ax += xsv * sVx[q];
            ay += xsv * sVy[q];
            az += xsv * sVz[q];
            #pragma unroll
            for (int j = 0; j < 5; ++j) rc[j] = rn[j];
            ca = na;
        }
        size_t dvi = (size_t)cur * H3;
        atomicAdd(&dv[dvi + ch],       ax);
        atomicAdd(&dv[dvi + 128 + ch], ay);
        atomicAdd(&dv[dvi + 256 + ch], az);
    } else {
        float4 rc[5], rn[5];
        LOAD_ROW(rc, 0);
        #pragma unroll
        for (int j = 0; j < 5; ++j) rn[j] = rc[j];
        u32 cb = P3[sJ[0] + 128 + ch];               // (pvv, vx)
        u32 cc = P3[sJ[0] + 256 + ch];               // (vy, vz)
        float ax = 0.f, ay = 0.f, az = 0.f;
        for (int q = 0; q < cnt; ++q) {
            int qn = q + 1;
            u32 nb = 0, nc = 0;
            if (qn < cnt) {
                LOAD_ROW(rn, qn);
                nb = P3[sJ[qn] + 128 + ch];
                nc = P3[sJ[qn] + 256 + ch];
            }
            if (sI[q] != cur) {
                size_t dvi = (size_t)cur * H3;
                atomicAdd(&dv[dvi + ch],       ax);
                atomicAdd(&dv[dvi + 128 + ch], ay);
                atomicAdd(&dv[dvi + 256 + ch], az);
                ax = ay = az = 0.f; cur = sI[q];
            }
            float w; DOT20(w, rc);
            float ex = sVx[q], ey = sVy[q], ez = sVz[q];
            float xvv   = w * sCut[q] * bflo(cb);
            float inner = bfhi(cb) * ex + bflo(cc) * ey + bfhi(cc) * ez;
            float tt    = inner * xvv;
            ax += tt * ex;
            ay += tt * ey;
            az += tt * ez;
            #pragma unroll
            for (int j = 0; j < 5; ++j) rc[j] = rn[j];
            cb = nb; cc = nc;
        }
        size_t dvi = (size_t)cur * H3;
        atomicAdd(&dv[dvi + ch],       ax);
        atomicAdd(&dv[dvi + 128 + ch], ay);
        atomicAdd(&dv[dvi + 256 + ch], az);
    }
}

extern "C" void kernel_launch(void* const* d_in, const int* in_sizes, int n_in,
                              void* d_out, int out_size, void* d_ws, size_t ws_size,
                              hipStream_t stream)
{
    const float* s    = (const float*)d_in[0];
    const float* v    = (const float*)d_in[1];
    const float* rbf  = (const float*)d_in[2];
    const float* cut  = (const float*)d_in[3];
    const float* evec = (const float*)d_in[4];
    const float* W1   = (const float*)d_in[5];
    const float* b1   = (const float*)d_in[6];
    const float* W2   = (const float*)d_in[7];
    const float* b2   = (const float*)d_in[8];
    const float* Wr   = (const float*)d_in[9];
    const float* br   = (const float*)d_in[10];
    const int*   eidx = (const int*)d_in[11];

    const int N = in_sizes[0] / HDIM;   // 20000
    const int E = in_sizes[3];          // 400000

    float* out = (float*)d_out;
    float* ds  = out;                      // [N, H]
    float* dv  = out + (size_t)N * HDIM;   // [N, 3, H]

    // workspace layout (256B aligned chunks)
    char* w = (char*)d_ws;
    u32* P3 = (u32*)w;                     w += ((size_t)N * H3 * 4 + 255) / 256 * 256;
    int* counts = (int*)w;                 w += ((size_t)N * 4 + 255) / 256 * 256;
    int* rstart = (int*)w;                 w += ((size_t)(N + 1) * 4 + 255) / 256 * 256;
    int* cursor = (int*)w;                 w += ((size_t)N * 4 + 255) / 256 * 256;
    int* eord   = (int*)w;

    hipMemsetAsync(d_out, 0, (size_t)out_size * sizeof(float), stream);
    hipMemsetAsync(counts, 0, (size_t)N * sizeof(int), stream);

    node_mlp_kernel<<<(N + NPB - 1) / NPB, 128, 0, stream>>>(s, W1, b1, W2, b2, v, P3, N);
    hist_kernel<<<(E + 255) / 256, 256, 0, stream>>>(eidx, counts, E);
    scan_kernel<<<1, 1024, 0, stream>>>(counts, rstart, cursor, N);
    scatter_kernel<<<(E + 255) / 256, 256, 0, stream>>>(eidx, cursor, eord, E);
    edge_stream_kernel<<<(E + EPB - 1) / EPB, TPB, 0, stream>>>(eord, eidx, rbf, cut,
                                                                evec, Wr, br, P3,
                                                                ds, dv, E);
}

// Round 11
// 378.406 us; speedup vs baseline: 1.3085x; 1.3085x over previous
//
#include <hip/hip_runtime.h>
#include <hip/hip_bf16.h>

#define HDIM 128
#define H3   384
#define RDIM 20
#define NPB  16    // nodes per block (node MLP)
#define EPB  128   // edges per block (edge stream kernel)
#define TPB  384   // 3 roles x 128 channels

typedef unsigned short u16;
typedef unsigned int   u32;

__device__ __forceinline__ u16 f2bf(float f) {
    __hip_bfloat16 h = __float2bfloat16(f);   // RNE
    return *(u16*)&h;
}
__device__ __forceinline__ float bflo(u32 u) {
    union { u32 i; float f; } x; x.i = u << 16; return x.f;
}
__device__ __forceinline__ float bfhi(u32 u) {
    union { u32 i; float f; } x; x.i = u & 0xffff0000u; return x.f;
}
__device__ __forceinline__ u32 pk(float lo, float hi) {
    return (u32)f2bf(lo) | ((u32)f2bf(hi) << 16);
}

// -------- Kernel 1: per-node MLP -> packed bf16 P3[node][3][128]; fuses v conv --------
__global__ __launch_bounds__(128) void node_mlp_kernel(
    const float* __restrict__ s, const float* __restrict__ W1,
    const float* __restrict__ b1, const float* __restrict__ W2,
    const float* __restrict__ b2, const float* __restrict__ v,
    u32* __restrict__ P3, int N)
{
    __shared__ float sS[NPB][HDIM];
    __shared__ float sH[NPB][HDIM];
    const int t  = threadIdx.x;
    const int n0 = blockIdx.x * NPB;

    #pragma unroll
    for (int n = 0; n < NPB; ++n) {
        int node = n0 + n;
        sS[n][t] = (node < N) ? s[(size_t)node * HDIM + t] : 0.f;
    }
    __syncthreads();

    float acc[NPB];
    #pragma unroll
    for (int n = 0; n < NPB; ++n) acc[n] = 0.f;
    for (int k = 0; k < HDIM; ++k) {
        float w = W1[k * HDIM + t];
        #pragma unroll
        for (int n = 0; n < NPB; ++n) acc[n] += sS[n][k] * w;
    }
    float bb = b1[t];
    #pragma unroll
    for (int n = 0; n < NPB; ++n) {
        float z = acc[n] + bb;
        sH[n][t] = z / (1.f + __expf(-z));   // silu
    }
    __syncthreads();

    float a0[NPB], a1[NPB], a2[NPB];
    #pragma unroll
    for (int n = 0; n < NPB; ++n) { a0[n] = 0.f; a1[n] = 0.f; a2[n] = 0.f; }
    for (int k2 = 0; k2 < HDIM / 2; ++k2) {
        float2 hv[NPB];
        #pragma unroll
        for (int n = 0; n < NPB; ++n) hv[n] = ((const float2*)sH[n])[k2];
        #pragma unroll
        for (int kk = 0; kk < 2; ++kk) {
            int k = 2 * k2 + kk;
            float w0 = W2[k * H3 + t];
            float w1 = W2[k * H3 + t + 128];
            float w2 = W2[k * H3 + t + 256];
            #pragma unroll
            for (int n = 0; n < NPB; ++n) {
                float h = kk ? hv[n].y : hv[n].x;
                a0[n] += h * w0;
                a1[n] += h * w1;
                a2[n] += h * w2;
            }
        }
    }
    float c0 = b2[t], c1 = b2[t + 128], c2 = b2[t + 256];
    #pragma unroll
    for (int n = 0; n < NPB; ++n) {
        int node = n0 + n;
        if (node < N) {
            size_t vb = (size_t)node * H3;
            float vx = v[vb + t], vy = v[vb + 128 + t], vz = v[vb + 256 + t];
            size_t pb = (size_t)node * H3 + t;
            P3[pb]       = pk(a0[n] + c0, a1[n] + c1);   // (pss, psv)
            P3[pb + 128] = pk(a2[n] + c2, vx);           // (pvv, vx)
            P3[pb + 256] = pk(vy, vz);                   // (vy, vz)
        }
    }
}

// -------- CSR build (sort edges by destination) --------
__global__ void hist_kernel(const int* __restrict__ eidx, int* __restrict__ counts, int E)
{
    int e = blockIdx.x * 256 + threadIdx.x;
    if (e < E) atomicAdd(&counts[eidx[e]], 1);
}

__global__ __launch_bounds__(1024) void scan_kernel(
    const int* __restrict__ counts, int* __restrict__ rstart,
    int* __restrict__ cursor, int N)
{
    __shared__ int part[1024];
    const int t = threadIdx.x;
    const int C = 20;
    int loc[C];
    int s = 0;
    #pragma unroll
    for (int q = 0; q < C; ++q) {
        int idx = t * C + q;
        int c = (idx < N) ? counts[idx] : 0;
        loc[q] = s; s += c;
    }
    part[t] = s;
    __syncthreads();
    for (int off = 1; off < 1024; off <<= 1) {
        int vv = (t >= off) ? part[t - off] : 0;
        __syncthreads();
        part[t] += vv;
        __syncthreads();
    }
    int boff = (t > 0) ? part[t - 1] : 0;
    #pragma unroll
    for (int q = 0; q < C; ++q) {
        int idx = t * C + q;
        if (idx < N) {
            int st = boff + loc[q];
            rstart[idx] = st;
            cursor[idx] = st;
        }
    }
    if (t == 1023) rstart[N] = part[1023];
}

__global__ void scatter_kernel(const int* __restrict__ eidx, int* __restrict__ cursor,
                               int* __restrict__ eord, int E)
{
    int e = blockIdx.x * 256 + threadIdx.x;
    if (e < E) {
        int i = eidx[e];
        int pos = atomicAdd(&cursor[i], 1);
        eord[pos] = e;
    }
}

// dot of LDS-broadcast rbf row q with the 20 named Wr scalars
#define DOT20N(res, q) {                                              \
    const float4* r4_ = (const float4*)sRbf[q];                       \
    float4 r0_ = r4_[0], r1_ = r4_[1], r2_ = r4_[2],                  \
           r3_ = r4_[3], r4v_ = r4_[4];                               \
    res = brv                                                         \
        + r0_.x*w00 + r0_.y*w01 + r0_.z*w02 + r0_.w*w03               \
        + r1_.x*w04 + r1_.y*w05 + r1_.z*w06 + r1_.w*w07               \
        + r2_.x*w08 + r2_.y*w09 + r2_.z*w10 + r2_.w*w11               \
        + r3_.x*w12 + r3_.y*w13 + r3_.z*w14 + r3_.w*w15               \
        + r4v_.x*w16 + r4v_.y*w17 + r4v_.z*w18 + r4v_.w*w19; }

// -------- Kernel 2: edge streaming, 3 roles, rbf in LDS, named-scalar Wr --------
// Role 0: ds += xss. Role 1: dv += xsv*e. Role 2: dv += (inner*xvv)*e.
// The dv split is valid because both parts flush via atomicAdd.
__global__ __launch_bounds__(TPB) void edge_stream_kernel(
    const int* __restrict__ eord, const int* __restrict__ eidx,
    const float* __restrict__ rbf, const float* __restrict__ cutoff,
    const float* __restrict__ evec, const float* __restrict__ Wr,
    const float* __restrict__ br, const u32* __restrict__ P3,
    float* __restrict__ ds, float* __restrict__ dv, int E)
{
    const int t    = threadIdx.x;
    const int ch   = t & (HDIM - 1);
    const int role = t >> 7;            // 0,1,2
    const int base = blockIdx.x * EPB;
    const int cnt  = min(EPB, E - base);

    // 20 Wr values for this thread's single output column (col == t since TPB==H3),
    // as NAMED scalars — arrays kept getting demoted to scratch (r10: VGPR=24).
    const float* wc = Wr + t;
    const float w00 = wc[0*H3],  w01 = wc[1*H3],  w02 = wc[2*H3],  w03 = wc[3*H3];
    const float w04 = wc[4*H3],  w05 = wc[5*H3],  w06 = wc[6*H3],  w07 = wc[7*H3];
    const float w08 = wc[8*H3],  w09 = wc[9*H3],  w10 = wc[10*H3], w11 = wc[11*H3];
    const float w12 = wc[12*H3], w13 = wc[13*H3], w14 = wc[14*H3], w15 = wc[15*H3];
    const float w16 = wc[16*H3], w17 = wc[17*H3], w18 = wc[18*H3], w19 = wc[19*H3];
    const float brv = br[t];

    __shared__ int   sI[EPB], sJ[EPB];
    __shared__ float sCut[EPB], sVx[EPB], sVy[EPB], sVz[EPB];
    __shared__ __attribute__((aligned(16))) float sRbf[EPB][RDIM];

    if (t < cnt) {
        int e   = eord[base + t];
        sI[t]   = eidx[e];
        sJ[t]   = eidx[E + e] * H3;
        sCut[t] = cutoff[e];
        sVx[t]  = evec[3 * e];
        sVy[t]  = evec[3 * e + 1];
        sVz[t]  = evec[3 * e + 2];
        const float4* rp = (const float4*)(rbf + (size_t)e * RDIM);
        float4* dst = (float4*)sRbf[t];
        #pragma unroll
        for (int j = 0; j < 5; ++j) dst[j] = rp[j];
    }
    __syncthreads();

    int cur = sI[0];

    if (role == 0) {
        u32 ca = P3[sJ[0] + ch];
        float accs = 0.f;
        for (int q = 0; q < cnt; ++q) {
            u32 na = 0;
            if (q + 1 < cnt) na = P3[sJ[q + 1] + ch];
            if (sI[q] != cur) {                      // uniform branch
                atomicAdd(&ds[(size_t)cur * HDIM + ch], accs);
                accs = 0.f; cur = sI[q];
            }
            float w; DOT20N(w, q);
            accs += w * sCut[q] * bflo(ca);
            ca = na;
        }
        atomicAdd(&ds[(size_t)cur * HDIM + ch], accs);
    } else if (role == 1) {
        u32 ca = P3[sJ[0] + ch];                     // psv in hi half
        float ax = 0.f, ay = 0.f, az = 0.f;
        for (int q = 0; q < cnt; ++q) {
            u32 na = 0;
            if (q + 1 < cnt) na = P3[sJ[q + 1] + ch];
            if (sI[q] != cur) {
                size_t dvi = (size_t)cur * H3;
                atomicAdd(&dv[dvi + ch],       ax);
                atomicAdd(&dv[dvi + 128 + ch], ay);
                atomicAdd(&dv[dvi + 256 + ch], az);
                ax = ay = az = 0.f; cur = sI[q];
            }
            float w; DOT20N(w, q);
            float xsv = w * sCut[q] * bfhi(ca);
            ax += xsv * sVx[q];
            ay += xsv * sVy[q];
            az += xsv * sVz[q];
            ca = na;
        }
        size_t dvi = (size_t)cur * H3;
        atomicAdd(&dv[dvi + ch],       ax);
        atomicAdd(&dv[dvi + 128 + ch], ay);
        atomicAdd(&dv[dvi + 256 + ch], az);
    } else {
        u32 cb = P3[sJ[0] + 128 + ch];               // (pvv, vx)
        u32 cc = P3[sJ[0] + 256 + ch];               // (vy, vz)
        float ax = 0.f, ay = 0.f, az = 0.f;
        for (int q = 0; q < cnt; ++q) {
            u32 nb = 0, nc = 0;
            if (q + 1 < cnt) {
                nb = P3[sJ[q + 1] + 128 + ch];
                nc = P3[sJ[q + 1] + 256 + ch];
            }
            if (sI[q] != cur) {
                size_t dvi = (size_t)cur * H3;
                atomicAdd(&dv[dvi + ch],       ax);
                atomicAdd(&dv[dvi + 128 + ch], ay);
                atomicAdd(&dv[dvi + 256 + ch], az);
                ax = ay = az = 0.f; cur = sI[q];
            }
            float w; DOT20N(w, q);
            float ex = sVx[q], ey = sVy[q], ez = sVz[q];
            float xvv   = w * sCut[q] * bflo(cb);
            float inner = bfhi(cb) * ex + bflo(cc) * ey + bfhi(cc) * ez;
            float tt    = inner * xvv;
            ax += tt * ex;
            ay += tt * ey;
            az += tt * ez;
            cb = nb; cc = nc;
        }
        size_t dvi = (size_t)cur * H3;
        atomicAdd(&dv[dvi + ch],       ax);
        atomicAdd(&dv[dvi + 128 + ch], ay);
        atomicAdd(&dv[dvi + 256 + ch], az);
    }
}

extern "C" void kernel_launch(void* const* d_in, const int* in_sizes, int n_in,
                              void* d_out, int out_size, void* d_ws, size_t ws_size,
                              hipStream_t stream)
{
    const float* s    = (const float*)d_in[0];
    const float* v    = (const float*)d_in[1];
    const float* rbf  = (const float*)d_in[2];
    const float* cut  = (const float*)d_in[3];
    const float* evec = (const float*)d_in[4];
    const float* W1   = (const float*)d_in[5];
    const float* b1   = (const float*)d_in[6];
    const float* W2   = (const float*)d_in[7];
    const float* b2   = (const float*)d_in[8];
    const float* Wr   = (const float*)d_in[9];
    const float* br   = (const float*)d_in[10];
    const int*   eidx = (const int*)d_in[11];

    const int N = in_sizes[0] / HDIM;   // 20000
    const int E = in_sizes[3];          // 400000

    float* out = (float*)d_out;
    float* ds  = out;                      // [N, H]
    float* dv  = out + (size_t)N * HDIM;   // [N, 3, H]

    // workspace layout (256B aligned chunks)
    char* w = (char*)d_ws;
    u32* P3 = (u32*)w;                     w += ((size_t)N * H3 * 4 + 255) / 256 * 256;
    int* counts = (int*)w;                 w += ((size_t)N * 4 + 255) / 256 * 256;
    int* rstart = (int*)w;                 w += ((size_t)(N + 1) * 4 + 255) / 256 * 256;
    int* cursor = (int*)w;                 w += ((size_t)N * 4 + 255) / 256 * 256;
    int* eord   = (int*)w;

    hipMemsetAsync(d_out, 0, (size_t)out_size * sizeof(float), stream);
    hipMemsetAsync(counts, 0, (size_t)N * sizeof(int), stream);

    node_mlp_kernel<<<(N + NPB - 1) / NPB, 128, 0, stream>>>(s, W1, b1, W2, b2, v, P3, N);
    hist_kernel<<<(E + 255) / 256, 256, 0, stream>>>(eidx, counts, E);
    scan_kernel<<<1, 1024, 0, stream>>>(counts, rstart, cursor, N);
    scatter_kernel<<<(E + 255) / 256, 256, 0, stream>>>(eidx, cursor, eord, E);
    edge_stream_kernel<<<(E + EPB - 1) / EPB, TPB, 0, stream>>>(eord, eidx, rbf, cut,
                                                                evec, Wr, br, P3,
                                                                ds, dv, E);
}

// Round 12
// 319.793 us; speedup vs baseline: 1.5484x; 1.1833x over previous
//
#include <hip/hip_runtime.h>
#include <hip/hip_bf16.h>

#define HDIM 128
#define H3   384
#define RDIM 20
#define NPB  16    // nodes per block (node MLP)
#define EPB  128   // edges per block (edge kernel)

typedef unsigned short u16;
typedef unsigned int   u32;
typedef __attribute__((ext_vector_type(8))) short short8v;
typedef __attribute__((ext_vector_type(4))) float f32x4;

__device__ __forceinline__ u16 f2bf(float f) {
    __hip_bfloat16 h = __float2bfloat16(f);   // RNE
    return *(u16*)&h;
}
__device__ __forceinline__ float bf2f(u16 u) {
    union { u32 i; float f; } x; x.i = (u32)u << 16; return x.f;
}
__device__ __forceinline__ float bflo(u32 u) {
    union { u32 i; float f; } x; x.i = u << 16; return x.f;
}
__device__ __forceinline__ float bfhi(u32 u) {
    union { u32 i; float f; } x; x.i = u & 0xffff0000u; return x.f;
}
__device__ __forceinline__ u32 pk(float lo, float hi) {
    return (u32)f2bf(lo) | ((u32)f2bf(hi) << 16);
}

// -------- Kernel 1: per-node MLP -> packed bf16 P3[node][3][128]; fuses v conv --------
__global__ __launch_bounds__(128) void node_mlp_kernel(
    const float* __restrict__ s, const float* __restrict__ W1,
    const float* __restrict__ b1, const float* __restrict__ W2,
    const float* __restrict__ b2, const float* __restrict__ v,
    u32* __restrict__ P3, int N)
{
    __shared__ float sS[NPB][HDIM];
    __shared__ float sH[NPB][HDIM];
    const int t  = threadIdx.x;
    const int n0 = blockIdx.x * NPB;

    #pragma unroll
    for (int n = 0; n < NPB; ++n) {
        int node = n0 + n;
        sS[n][t] = (node < N) ? s[(size_t)node * HDIM + t] : 0.f;
    }
    __syncthreads();

    float acc[NPB];
    #pragma unroll
    for (int n = 0; n < NPB; ++n) acc[n] = 0.f;
    for (int k = 0; k < HDIM; ++k) {
        float w = W1[k * HDIM + t];
        #pragma unroll
        for (int n = 0; n < NPB; ++n) acc[n] += sS[n][k] * w;
    }
    float bb = b1[t];
    #pragma unroll
    for (int n = 0; n < NPB; ++n) {
        float z = acc[n] + bb;
        sH[n][t] = z / (1.f + __expf(-z));   // silu
    }
    __syncthreads();

    float a0[NPB], a1[NPB], a2[NPB];
    #pragma unroll
    for (int n = 0; n < NPB; ++n) { a0[n] = 0.f; a1[n] = 0.f; a2[n] = 0.f; }
    for (int k2 = 0; k2 < HDIM / 2; ++k2) {
        float2 hv[NPB];
        #pragma unroll
        for (int n = 0; n < NPB; ++n) hv[n] = ((const float2*)sH[n])[k2];
        #pragma unroll
        for (int kk = 0; kk < 2; ++kk) {
            int k = 2 * k2 + kk;
            float w0 = W2[k * H3 + t];
            float w1 = W2[k * H3 + t + 128];
            float w2 = W2[k * H3 + t + 256];
            #pragma unroll
            for (int n = 0; n < NPB; ++n) {
                float h = kk ? hv[n].y : hv[n].x;
                a0[n] += h * w0;
                a1[n] += h * w1;
                a2[n] += h * w2;
            }
        }
    }
    float c0 = b2[t], c1 = b2[t + 128], c2 = b2[t + 256];
    #pragma unroll
    for (int n = 0; n < NPB; ++n) {
        int node = n0 + n;
        if (node < N) {
            size_t vb = (size_t)node * H3;
            float vx = v[vb + t], vy = v[vb + 128 + t], vz = v[vb + 256 + t];
            size_t pb = (size_t)node * H3 + t;
            P3[pb]       = pk(a0[n] + c0, a1[n] + c1);   // (pss, psv)
            P3[pb + 128] = pk(a2[n] + c2, vx);           // (pvv, vx)
            P3[pb + 256] = pk(vy, vz);                   // (vy, vz)
        }
    }
}

// -------- CSR build (sort edges by destination) --------
__global__ void hist_kernel(const int* __restrict__ eidx, int* __restrict__ counts, int E)
{
    int e = blockIdx.x * 256 + threadIdx.x;
    if (e < E) atomicAdd(&counts[eidx[e]], 1);
}

__global__ __launch_bounds__(1024) void scan_kernel(
    const int* __restrict__ counts, int* __restrict__ rstart,
    int* __restrict__ cursor, int N)
{
    __shared__ int part[1024];
    const int t = threadIdx.x;
    const int C = 20;
    int loc[C];
    int s = 0;
    #pragma unroll
    for (int q = 0; q < C; ++q) {
        int idx = t * C + q;
        int c = (idx < N) ? counts[idx] : 0;
        loc[q] = s; s += c;
    }
    part[t] = s;
    __syncthreads();
    for (int off = 1; off < 1024; off <<= 1) {
        int vv = (t >= off) ? part[t - off] : 0;
        __syncthreads();
        part[t] += vv;
        __syncthreads();
    }
    int boff = (t > 0) ? part[t - 1] : 0;
    #pragma unroll
    for (int q = 0; q < C; ++q) {
        int idx = t * C + q;
        if (idx < N) {
            int st = boff + loc[q];
            rstart[idx] = st;
            cursor[idx] = st;
        }
    }
    if (t == 1023) rstart[N] = part[1023];
}

__global__ void scatter_kernel(const int* __restrict__ eidx, int* __restrict__ cursor,
                               int* __restrict__ eord, int E)
{
    int e = blockIdx.x * 256 + threadIdx.x;
    if (e < E) {
        int i = eidx[e];
        int pos = atomicAdd(&cursor[i], 1);
        eord[pos] = e;
    }
}

// -------- Kernel W: Ws[pos][384] = bf16((rbf[eord[pos]] @ Wr + br) * cutoff) --------
// MFMA 16x16x32 bf16; fragment mapping verified in round 4 (passed absmax 0.5).
// Written in destination-sorted (pos) order so the edge kernel reads sequentially.
__global__ __launch_bounds__(256) void wgemm_kernel(
    const int* __restrict__ eord, const float* __restrict__ rbf,
    const float* __restrict__ cutoff, const float* __restrict__ Wr,
    const float* __restrict__ br, u16* __restrict__ Ws, int E)
{
    const int lane    = threadIdx.x & 63;
    const int wave    = threadIdx.x >> 6;
    const int g       = lane >> 4;     // k-group
    const int m       = lane & 15;     // row within 16-pos group / col within tile
    const int colhalf = wave & 1;      // cols [0,192) or [192,384)
    const int wgrp    = wave >> 1;     // which 16-pos subgroup of the 32

    // B-frags (Wr bf16) + bias, held in VGPRs for the whole kernel (r4-proven).
    short8v bfrag[12];
    float   brt[12];
    #pragma unroll
    for (int n = 0; n < 12; ++n) {
        int col = colhalf * 192 + n * 16 + m;
        short8v f;
        #pragma unroll
        for (int j = 0; j < 8; ++j) {
            int k = 8 * g + j;
            f[j] = (k < RDIM) ? (short)f2bf(Wr[k * H3 + col]) : (short)0;
        }
        bfrag[n] = f;
        brt[n] = br[col];
    }

    const int PBI = 256;   // positions per block
    for (int it = 0; it < PBI / 32; ++it) {
        int pbase = blockIdx.x * PBI + it * 32 + wgrp * 16;
        if (pbase >= E) break;

        // A-frag: lane row m = position pbase+m, k = 8g+j (zero for k>=20 / OOB)
        short8v af;
        int posA = pbase + m;
        if (posA < E && g < 3) {
            const float* rr = rbf + (size_t)eord[posA] * RDIM;
            if (g < 2) {
                float4 r0 = *(const float4*)(rr + 8 * g);
                float4 r1 = *(const float4*)(rr + 8 * g + 4);
                af[0] = (short)f2bf(r0.x); af[1] = (short)f2bf(r0.y);
                af[2] = (short)f2bf(r0.z); af[3] = (short)f2bf(r0.w);
                af[4] = (short)f2bf(r1.x); af[5] = (short)f2bf(r1.y);
                af[6] = (short)f2bf(r1.z); af[7] = (short)f2bf(r1.w);
            } else {
                float4 r0 = *(const float4*)(rr + 16);
                af[0] = (short)f2bf(r0.x); af[1] = (short)f2bf(r0.y);
                af[2] = (short)f2bf(r0.z); af[3] = (short)f2bf(r0.w);
                af[4] = 0; af[5] = 0; af[6] = 0; af[7] = 0;
            }
        } else {
            #pragma unroll
            for (int j = 0; j < 8; ++j) af[j] = 0;
        }

        // cutoff for this lane's 4 output rows (C rows = 4g+r)
        float cut[4];
        #pragma unroll
        for (int r = 0; r < 4; ++r) {
            int pos = pbase + 4 * g + r;
            cut[r] = (pos < E) ? cutoff[eord[pos]] : 0.f;
        }

        #pragma unroll
        for (int n = 0; n < 12; ++n) {
            f32x4 c = {0.f, 0.f, 0.f, 0.f};
            c = __builtin_amdgcn_mfma_f32_16x16x32_bf16(af, bfrag[n], c, 0, 0, 0);
            int col = colhalf * 192 + n * 16 + m;
            #pragma unroll
            for (int r = 0; r < 4; ++r) {
                int pos = pbase + 4 * g + r;
                if (pos < E)
                    Ws[(size_t)pos * H3 + col] = f2bf((c[r] + brt[n]) * cut[r]);
            }
        }
    }
}

// -------- Kernel 2: edge streaming — sequential Ws read + P3 gather + run-flush --------
__global__ __launch_bounds__(128) void edge_kernel(
    const int* __restrict__ eord, const int* __restrict__ eidx,
    const float* __restrict__ evec, const u16* __restrict__ Ws,
    const u32* __restrict__ P3, float* __restrict__ ds,
    float* __restrict__ dv, int E)
{
    const int t    = threadIdx.x;
    const int base = blockIdx.x * EPB;
    const int cnt  = min(EPB, E - base);

    __shared__ int   sI[EPB], sJ[EPB];
    __shared__ float sVx[EPB], sVy[EPB], sVz[EPB];

    if (t < cnt) {
        int e  = eord[base + t];
        sI[t]  = eidx[e];
        sJ[t]  = eidx[E + e] * H3;
        sVx[t] = evec[3 * e];
        sVy[t] = evec[3 * e + 1];
        sVz[t] = evec[3 * e + 2];
    }
    __syncthreads();

    const u16* wp = Ws + (size_t)base * H3 + t;   // sorted order: sequential rows

    int   cur  = sI[0];
    float accs = 0.f, accx = 0.f, accy = 0.f, accz = 0.f;

    u32 ca, cb, cc; u16 w0c, w1c, w2c;
    {
        int idx = sJ[0] + t;
        ca = P3[idx]; cb = P3[idx + 128]; cc = P3[idx + 256];
        w0c = wp[0]; w1c = wp[128]; w2c = wp[256];
    }

    for (int q = 0; q < cnt; ++q) {
        u32 na = 0, nb = 0, nc = 0; u16 w0n = 0, w1n = 0, w2n = 0;
        if (q + 1 < cnt) {
            int idx = sJ[q + 1] + t;
            na = P3[idx]; nb = P3[idx + 128]; nc = P3[idx + 256];
            const u16* wq = wp + (size_t)(q + 1) * H3;
            w0n = wq[0]; w1n = wq[128]; w2n = wq[256];
        }
        if (sI[q] != cur) {                  // run boundary (block-uniform branch)
            atomicAdd(&ds[(size_t)cur * HDIM + t], accs);
            size_t dvi = (size_t)cur * H3;
            atomicAdd(&dv[dvi + t],       accx);
            atomicAdd(&dv[dvi + 128 + t], accy);
            atomicAdd(&dv[dvi + 256 + t], accz);
            accs = accx = accy = accz = 0.f;
            cur = sI[q];
        }
        float w0 = bf2f(w0c), w1 = bf2f(w1c), w2 = bf2f(w2c);
        float ex = sVx[q], ey = sVy[q], ez = sVz[q];
        float pss = bflo(ca), psv = bfhi(ca);
        float pvv = bflo(cb), vx  = bfhi(cb);
        float vy  = bflo(cc), vz  = bfhi(cc);
        float xss = w0 * pss;
        float xsv = w1 * psv;
        float xvv = w2 * pvv;
        float inner = vx * ex + vy * ey + vz * ez;
        float coef  = xsv + inner * xvv;
        accs += xss;
        accx += coef * ex;
        accy += coef * ey;
        accz += coef * ez;
        ca = na; cb = nb; cc = nc;
        w0c = w0n; w1c = w1n; w2c = w2n;
    }
    atomicAdd(&ds[(size_t)cur * HDIM + t], accs);
    size_t dvi = (size_t)cur * H3;
    atomicAdd(&dv[dvi + t],       accx);
    atomicAdd(&dv[dvi + 128 + t], accy);
    atomicAdd(&dv[dvi + 256 + t], accz);
}

// -------- Fallback (round-7 kernel, 197 µs): used only if ws too small for Ws --------
__global__ __launch_bounds__(128, 4) void edge_stream_fallback(
    const int* __restrict__ eord, const int* __restrict__ eidx,
    const float* __restrict__ rbf, const float* __restrict__ cutoff,
    const float* __restrict__ evec, const float* __restrict__ Wr,
    const float* __restrict__ br, const u32* __restrict__ P3,
    float* __restrict__ ds, float* __restrict__ dv, int E)
{
    const int t    = threadIdx.x;
    const int base = blockIdx.x * 64;
    const int cnt  = min(64, E - base);

    float wr[3 * RDIM];
    #pragma unroll
    for (int k = 0; k < RDIM; ++k) {
        wr[k]            = Wr[k * H3 + t];
        wr[RDIM + k]     = Wr[k * H3 + t + 128];
        wr[2 * RDIM + k] = Wr[k * H3 + t + 256];
    }
    const float br0 = br[t], br1 = br[t + 128], br2 = br[t + 256];

    __shared__ int   sI[64], sJ[64];
    __shared__ float sCut[64], sVx[64], sVy[64], sVz[64];
    __shared__ __attribute__((aligned(16))) float sRbf[64][RDIM];

    if (t < cnt) {
        int e   = eord[base + t];
        sI[t]   = eidx[e];
        sJ[t]   = eidx[E + e] * H3;
        sCut[t] = cutoff[e];
        sVx[t]  = evec[3 * e];
        sVy[t]  = evec[3 * e + 1];
        sVz[t]  = evec[3 * e + 2];
        const float4* rr = (const float4*)(rbf + (size_t)e * RDIM);
        float4* dst = (float4*)sRbf[t];
        #pragma unroll
        for (int j = 0; j < 5; ++j) dst[j] = rr[j];
    }
    __syncthreads();

    u32 ca, cb, cc;
    {
        int idx = sJ[0] + t;
        ca = P3[idx]; cb = P3[idx + 128]; cc = P3[idx + 256];
    }
    int   cur  = sI[0];
    float accs = 0.f, accx = 0.f, accy = 0.f, accz = 0.f;

    for (int q = 0; q < cnt; ++q) {
        u32 na = 0, nb = 0, nc = 0;
        if (q + 1 < cnt) {
            int idx = sJ[q + 1] + t;
            na = P3[idx]; nb = P3[idx + 128]; nc = P3[idx + 256];
        }
        if (sI[q] != cur) {
            atomicAdd(&ds[(size_t)cur * HDIM + t], accs);
            size_t dvi = (size_t)cur * H3;
            atomicAdd(&dv[dvi + t],       accx);
            atomicAdd(&dv[dvi + 128 + t], accy);
            atomicAdd(&dv[dvi + 256 + t], accz);
            accs = accx = accy = accz = 0.f;
            cur = sI[q];
        }
        const float4* r4 = (const float4*)sRbf[q];
        float w0 = 0.f, w1 = 0.f, w2 = 0.f;
        #pragma unroll
        for (int k4 = 0; k4 < 5; ++k4) {
            float4 r = r4[k4];
            w0 += r.x*wr[4*k4]        + r.y*wr[4*k4+1]        + r.z*wr[4*k4+2]        + r.w*wr[4*k4+3];
            w1 += r.x*wr[RDIM+4*k4]   + r.y*wr[RDIM+4*k4+1]   + r.z*wr[RDIM+4*k4+2]   + r.w*wr[RDIM+4*k4+3];
            w2 += r.x*wr[2*RDIM+4*k4] + r.y*wr[2*RDIM+4*k4+1] + r.z*wr[2*RDIM+4*k4+2] + r.w*wr[2*RDIM+4*k4+3];
        }
        float cu = sCut[q];
        float ex = sVx[q], ey = sVy[q], ez = sVz[q];
        float pss = bflo(ca), psv = bfhi(ca);
        float pvv = bflo(cb), vx  = bfhi(cb);
        float vy  = bflo(cc), vz  = bfhi(cc);
        float xss = (w0 + br0) * cu * pss;
        float xsv = (w1 + br1) * cu * psv;
        float xvv = (w2 + br2) * cu * pvv;
        float inner = vx * ex + vy * ey + vz * ez;
        float coef  = xsv + inner * xvv;
        accs += xss;
        accx += coef * ex;
        accy += coef * ey;
        accz += coef * ez;
        ca = na; cb = nb; cc = nc;
    }
    atomicAdd(&ds[(size_t)cur * HDIM + t], accs);
    size_t dvi = (size_t)cur * H3;
    atomicAdd(&dv[dvi + t],       accx);
    atomicAdd(&dv[dvi + 128 + t], accy);
    atomicAdd(&dv[dvi + 256 + t], accz);
}

extern "C" void kernel_launch(void* const* d_in, const int* in_sizes, int n_in,
                              void* d_out, int out_size, void* d_ws, size_t ws_size,
                              hipStream_t stream)
{
    const float* s    = (const float*)d_in[0];
    const float* v    = (const float*)d_in[1];
    const float* rbf  = (const float*)d_in[2];
    const float* cut  = (const float*)d_in[3];
    const float* evec = (const float*)d_in[4];
    const float* W1   = (const float*)d_in[5];
    const float* b1   = (const float*)d_in[6];
    const float* W2   = (const float*)d_in[7];
    const float* b2   = (const float*)d_in[8];
    const float* Wr   = (const float*)d_in[9];
    const float* br   = (const float*)d_in[10];
    const int*   eidx = (const int*)d_in[11];

    const int N = in_sizes[0] / HDIM;   // 20000
    const int E = in_sizes[3];          // 400000

    float* out = (float*)d_out;
    float* ds  = out;                      // [N, H]
    float* dv  = out + (size_t)N * HDIM;   // [N, 3, H]

    // workspace layout (256B aligned chunks); Ws last (large, optional)
    char* w0 = (char*)d_ws;
    char* w  = w0;
    u32* P3 = (u32*)w;                     w += ((size_t)N * H3 * 4 + 255) / 256 * 256;
    int* counts = (int*)w;                 w += ((size_t)N * 4 + 255) / 256 * 256;
    int* rstart = (int*)w;                 w += ((size_t)(N + 1) * 4 + 255) / 256 * 256;
    int* cursor = (int*)w;                 w += ((size_t)N * 4 + 255) / 256 * 256;
    int* eord   = (int*)w;                 w += ((size_t)E * 4 + 255) / 256 * 256;
    u16* Ws     = (u16*)w;                 w += (size_t)E * H3 * 2;
    bool haveWs = ((size_t)(w - w0) <= ws_size);

    hipMemsetAsync(d_out, 0, (size_t)out_size * sizeof(float), stream);
    hipMemsetAsync(counts, 0, (size_t)N * sizeof(int), stream);

    node_mlp_kernel<<<(N + NPB - 1) / NPB, 128, 0, stream>>>(s, W1, b1, W2, b2, v, P3, N);
    hist_kernel<<<(E + 255) / 256, 256, 0, stream>>>(eidx, counts, E);
    scan_kernel<<<1, 1024, 0, stream>>>(counts, rstart, cursor, N);
    scatter_kernel<<<(E + 255) / 256, 256, 0, stream>>>(eidx, cursor, eord, E);

    if (haveWs) {
        wgemm_kernel<<<(E + 255) / 256, 256, 0, stream>>>(eord, rbf, cut, Wr, br, Ws, E);
        edge_kernel<<<(E + EPB - 1) / EPB, 128, 0, stream>>>(eord, eidx, evec, Ws, P3,
                                                             ds, dv, E);
    } else {
        edge_stream_fallback<<<(E + 63) / 64, 128, 0, stream>>>(eord, eidx, rbf, cut,
                                                                evec, Wr, br, P3,
                                                                ds, dv, E);
    }
}